// Round 5
// baseline (120.225 us; speedup 1.0000x reference)
//
#include <hip/hip_runtime.h>
#include <stdint.h>

#define PNUM 128
#define BATCH 8192
#define WPB 4                      // waves per block, 1 batch per wave
#define GRID1 (BATCH / WPB)        // 2048 blocks of 256 threads

typedef uint32_t u32;
typedef uint32_t u32x2 __attribute__((ext_vector_type(2)));
typedef uint32_t u32x4 __attribute__((ext_vector_type(4)));

// f32x2 -> f16x2 (RTZ) packed into one u32
__device__ __forceinline__ u32 cvt2u(float x, float y) {
    return __builtin_bit_cast(u32, __builtin_amdgcn_cvt_pkrtz(x, y));
}

// R10: smooth-L1 term on the F32 PIPE, consuming packed-f16 LDS data directly.
// R5-R9 evidence: wall time invariant (48-51us) across codegen/pipelining/
// atomic changes => VALU-ISSUE bound. 2560 VOP3P/wave at 4cyc = 34us floor,
// duty 34/49 = 70% == measured VALUBusy 67-71%. v_fma_mix_f32 unpacks f16
// halves for free (op_sel) and v_fma_f32 is HW-verified 2cyc (m07), so
// 8 f32-ops/pair (16cyc) beats 5 VOP3P/pair (20cyc) by 20% if the theory
// holds, and is ~neutral if mix is also 4cyc.
//   d   = q.half - p.half        v_fma_mix_f32 (p * -1.0 + q), f32-exact
//   m   = min(|d|, 1)            v_min_f32 with abs modifier (free)
//   t   = |d| - 0.5*m            v_fma_f32 with abs modifier (free)
//   acc += m * t                 v_fmac_f32
__device__ __forceinline__ void unitmix(u32 p, u32 q, float& acc) {
    float d0, m0, t0, d1, m1, t1;
    // lo halves (x coord)
    asm("v_fma_mix_f32 %0, %1, -1.0, %2 op_sel:[0,0,0] op_sel_hi:[1,0,1]"
        : "=v"(d0) : "v"(p), "v"(q));
    asm("v_min_f32 %0, abs(%1), 1.0" : "=v"(m0) : "v"(d0));
    asm("v_fma_f32 %0, %1, -0.5, abs(%2)" : "=v"(t0) : "v"(m0), "v"(d0));
    asm("v_fmac_f32 %0, %1, %2" : "+v"(acc) : "v"(m0), "v"(t0));
    // hi halves (y coord)
    asm("v_fma_mix_f32 %0, %1, -1.0, %2 op_sel:[1,0,1] op_sel_hi:[1,0,1]"
        : "=v"(d1) : "v"(p), "v"(q));
    asm("v_min_f32 %0, abs(%1), 1.0" : "=v"(m1) : "v"(d1));
    asm("v_fma_f32 %0, %1, -0.5, abs(%2)" : "=v"(t1) : "v"(m1), "v"(d1));
    asm("v_fmac_f32 %0, %1, %2" : "+v"(acc) : "v"(m1), "v"(t1));
}

#define DSR64(dst, addr, OFF) \
    asm volatile("ds_read_b64 %0, %1 offset:" OFF : "=v"(dst) : "v"(addr))
#define DSR128(dst, addr, OFF) \
    asm volatile("ds_read_b128 %0, %1 offset:" OFF : "=v"(dst) : "v"(addr))
#define WAITLG(N) \
    asm volatile("s_waitcnt lgkmcnt(" #N ")" ::: "memory"); \
    __builtin_amdgcn_sched_barrier(0)

#define COMPUTE(naC, nbC, q0C, q1C, Wv) \
    unitmix(q0C[0], Wv[0],  a00); \
    unitmix(q0C[1], Wv[1],  a00); \
    unitmix(q0C[2], naC[0], a00); \
    unitmix(q0C[3], naC[1], a00); \
    unitmix(q0C[0], Wv[1],  a01); \
    unitmix(q0C[1], naC[0], a01); \
    unitmix(q0C[2], naC[1], a01); \
    unitmix(q0C[3], nbC[0], a01); \
    unitmix(q1C[0], Wv[0],  a10); \
    unitmix(q1C[1], Wv[1],  a10); \
    unitmix(q1C[2], naC[0], a10); \
    unitmix(q1C[3], naC[1], a10); \
    unitmix(q1C[0], Wv[1],  a11); \
    unitmix(q1C[1], naC[0], a11); \
    unitmix(q1C[2], naC[1], a11); \
    unitmix(q1C[3], nbC[0], a11)

// One WAVE per batch, both preds. Lane k owns shifts {2k,2k+1}.
// gt ring (doubled, f16) + pred rows in per-wave LDS. Memory structure is
// R9's proven-neutral triple-buffered asm DS pipeline, UNCHANGED.
__global__ __launch_bounds__(64 * WPB, 8) void match_fused(
        const float* __restrict__ pred0,
        const float* __restrict__ pred1,
        const float* __restrict__ gt,
        float* __restrict__ ws) {
    __shared__ __align__(16) _Float16 lds[WPB][1024];  // ring 1024B | q0 512B | q1 512B
    __shared__ float bsum[WPB];

    const int t = threadIdx.x;
    const int k = t & 63;
    const int w = __builtin_amdgcn_readfirstlane(t >> 6);
    const int b = blockIdx.x * WPB + w;

    _Float16* base = lds[w];
    uint2* ringU = (uint2*)base;              // 128 entries (doubled ring)
    uint2* q0s   = (uint2*)(base + 512);      // byte 1024
    uint2* q1s   = (uint2*)(base + 768);      // byte 1536

    // ---- stage + f32->f16 convert (own wave's region; no barrier needed) ----
    const float4* gv4 = (const float4*)(gt    + (size_t)b * (PNUM * 2));
    const float4* p0v = (const float4*)(pred0 + (size_t)b * (PNUM * 2));
    const float4* p1v = (const float4*)(pred1 + (size_t)b * (PNUM * 2));
    {
        float4 g = gv4[k];
        uint2 gh = {cvt2u(g.x, g.y), cvt2u(g.z, g.w)};
        ringU[k] = gh; ringU[k + 64] = gh;
        float4 p = p0v[k];
        q0s[k] = (uint2){cvt2u(p.x, p.y), cvt2u(p.z, p.w)};
        p = p1v[k];
        q1s[k] = (uint2){cvt2u(p.x, p.y), cvt2u(p.z, p.w)};
    }

    // raw LDS byte addresses for asm DS ops
    u32 ldsb = (u32)(uintptr_t)base;
    u32 gA = ldsb + (u32)(k * 8);     // gather base (lane-sliding)
    u32 pA = ldsb + 1024;             // pred broadcast base (wave-uniform)

    asm volatile("s_waitcnt lgkmcnt(0)" ::: "memory");
    __builtin_amdgcn_sched_barrier(0);

    u32x2 na0, nb0, na1, nb1, na2, nb2;
    u32x4 q0b0, q1b0, q0b1, q1b1, q0b2, q1b2;

    // ---- prologue: W(iter0)=ring[k] into nb2; issue L0 (buf0), L1 (buf1) ----
    DSR64(nb2, gA, "0");
    DSR64(na0, gA, "8");   DSR64(nb0, gA, "16");
    DSR128(q0b0, pA, "0"); DSR128(q1b0, pA, "512");
    DSR64(na1, gA, "24");  DSR64(nb1, gA, "32");
    DSR128(q0b1, pA, "16"); DSR128(q1b1, pA, "528");

    float a00 = 0.f, a01 = 0.f, a10 = 0.f, a11 = 0.f;

    for (int bdy = 0; bdy < 10; ++bdy) {   // iters 3b, 3b+1, 3b+2 (0..29)
        WAITLG(4);
        COMPUTE(na0, nb0, q0b0, q1b0, nb2);
        DSR64(na2, gA, "40");  DSR64(nb2, gA, "48");
        DSR128(q0b2, pA, "32"); DSR128(q1b2, pA, "544");
        WAITLG(4);
        COMPUTE(na1, nb1, q0b1, q1b1, nb0);
        DSR64(na0, gA, "56");  DSR64(nb0, gA, "64");
        DSR128(q0b0, pA, "48"); DSR128(q1b0, pA, "560");
        WAITLG(4);
        COMPUTE(na2, nb2, q0b2, q1b2, nb1);
        DSR64(na1, gA, "72");  DSR64(nb1, gA, "80");
        DSR128(q0b1, pA, "64"); DSR128(q1b1, pA, "576");
        gA += 48; pA += 48;
    }
    // ---- epilogue: iters 30 (buf0, W=nb2) and 31 (buf1, W=nb0) ----
    WAITLG(4);
    COMPUTE(na0, nb0, q0b0, q1b0, nb2);
    WAITLG(0);
    COMPUTE(na1, nb1, q0b1, q1b1, nb0);

    // per-pred min over lane's 2 shifts, then over the wave
    float r0 = fminf(a00, a01);
    float r1 = fminf(a10, a11);
#pragma unroll
    for (int m = 32; m > 0; m >>= 1) {
        r0 = fminf(r0, __shfl_xor(r0, m, 64));
        r1 = fminf(r1, __shfl_xor(r1, m, 64));
    }

    if (k == 0) bsum[w] = r0 + r1;
    __syncthreads();
    if (t == 0) {
        // plain store, 2048 distinct addresses -> no cross-XCD RMW chain
        ws[blockIdx.x] = bsum[0] + bsum[1] + bsum[2] + bsum[3];
    }
}

// Second dispatch: sum 2048 per-block partials, scale, write out.
__global__ __launch_bounds__(256) void reduce_out(
        const float* __restrict__ ws, float* __restrict__ out) {
    const int t = threadIdx.x;
    const float4* w4 = (const float4*)ws;
    float4 v0 = w4[t];           // 256 * 4 = 1024 partials
    float4 v1 = w4[t + 256];     // + 1024 = 2048
    float s = ((v0.x + v0.y) + (v0.z + v0.w)) + ((v1.x + v1.y) + (v1.z + v1.w));
#pragma unroll
    for (int m = 32; m > 0; m >>= 1) s += __shfl_xor(s, m, 64);
    __shared__ float acc[4];
    const int w = t >> 6;
    if ((t & 63) == 0) acc[w] = s;
    __syncthreads();
    if (t == 0)
        out[0] = (acc[0] + acc[1] + acc[2] + acc[3]) * (1.0f / (2.0f * BATCH * PNUM));
}

extern "C" void kernel_launch(void* const* d_in, const int* in_sizes, int n_in,
                              void* d_out, int out_size, void* d_ws, size_t ws_size,
                              hipStream_t stream) {
    const float* pred0 = (const float*)d_in[0];
    const float* pred1 = (const float*)d_in[1];
    const float* gt    = (const float*)d_in[2];
    float* out = (float*)d_out;
    float* ws  = (float*)d_ws;      // 2048 floats = 8 KB of workspace

    match_fused<<<GRID1, 64 * WPB, 0, stream>>>(pred0, pred1, gt, ws);
    reduce_out<<<1, 256, 0, stream>>>(ws, out);
}

// Round 6
// 112.707 us; speedup vs baseline: 1.0667x; 1.0667x over previous
//
#include <hip/hip_runtime.h>
#include <stdint.h>

#define PNUM 128
#define BATCH 8192
#define WPB 4                      // waves per block, 1 batch per wave
#define GRID1 (BATCH / WPB)        // 2048 blocks of 256 threads

typedef uint32_t u32;
typedef uint32_t u32x2 __attribute__((ext_vector_type(2)));
typedef uint32_t u32x4 __attribute__((ext_vector_type(4)));

// f32x2 -> f16x2 (RTZ) packed into one u32
__device__ __forceinline__ u32 cvt2u(float x, float y) {
    return __builtin_bit_cast(u32, __builtin_amdgcn_cvt_pkrtz(x, y));
}

// One packed smooth-L1 term over both coords of a point pair, f32-accumulated.
// 5 packed instructions (R7-verified exact; R10 proved count is what matters:
// dur*VALUBusy scaled exactly with instr count across R9<->R10).
__device__ __forceinline__ void unit(u32 p, u32 q, float& acc, u32 cOne, u32 cNegHalf) {
    u32 d, a, m, t;
    asm("v_pk_add_f16 %0, %1, %2 neg_lo:[0,1] neg_hi:[0,1]" : "=v"(d) : "v"(p), "v"(q));
    asm("v_and_b32 %0, 0x7fff7fff, %1" : "=v"(a) : "v"(d));
    asm("v_pk_min_f16 %0, %1, %2" : "=v"(m) : "v"(a), "v"(cOne));
    asm("v_pk_fma_f16 %0, %1, %2, %3" : "=v"(t) : "v"(m), "v"(cNegHalf), "v"(a));
    asm("v_dot2_f32_f16 %0, %1, %2, %0" : "+v"(acc) : "v"(m), "v"(t));
}

#define DSR64(dst, addr) \
    asm volatile("ds_read_b64 %0, %1" : "=v"(dst) : "v"(addr))
#define DSR128(dst, addr, OFF) \
    asm volatile("ds_read_b128 %0, %1 offset:" OFF : "=v"(dst) : "v"(addr))
// one instruction, two 8B-aligned reads: entries +1 (na) and +2 (nb)
#define DSR2x64(dst, addr) \
    asm volatile("ds_read2_b64 %0, %1 offset0:1 offset1:2" : "=v"(dst) : "v"(addr))
#define WAITLG(N) \
    asm volatile("s_waitcnt lgkmcnt(" #N ")" ::: "memory"); \
    __builtin_amdgcn_sched_barrier(0)

// Issue iteration ii's 3 DS loads into buffer B, advance, wrap once (scalar
// branch; h0-staggered ring walk wraps seamlessly thanks to the doubled ring).
#define ISSUE(Bg, Bq0, Bq1) \
    DSR2x64(Bg, issGA); \
    DSR128(Bq0, issPA, "0"); \
    DSR128(Bq1, issPA, "512"); \
    issGA += 16; issPA += 16; \
    if (++ii == 32) { ii = 0; issGA = gA0; issPA = pA0; }

// 16 units of one iteration. G = [na0,na1,nb0,nb1]; W = previous iter's nb.
#define COMPUTE(G, Q0, Q1, W0, W1) \
    unit(Q0[0], W0,   a00, cOne, cNegHalf); \
    unit(Q0[1], W1,   a00, cOne, cNegHalf); \
    unit(Q0[2], G[0], a00, cOne, cNegHalf); \
    unit(Q0[3], G[1], a00, cOne, cNegHalf); \
    unit(Q0[0], W1,   a01, cOne, cNegHalf); \
    unit(Q0[1], G[0], a01, cOne, cNegHalf); \
    unit(Q0[2], G[1], a01, cOne, cNegHalf); \
    unit(Q0[3], G[2], a01, cOne, cNegHalf); \
    unit(Q1[0], W0,   a10, cOne, cNegHalf); \
    unit(Q1[1], W1,   a10, cOne, cNegHalf); \
    unit(Q1[2], G[0], a10, cOne, cNegHalf); \
    unit(Q1[3], G[1], a10, cOne, cNegHalf); \
    unit(Q1[0], W1,   a11, cOne, cNegHalf); \
    unit(Q1[1], G[0], a11, cOne, cNegHalf); \
    unit(Q1[2], G[1], a11, cOne, cNegHalf); \
    unit(Q1[3], G[2], a11, cOne, cNegHalf)

// R11 theory: R9's dur(49.3) - VALU-busy(33.5) = 15.8us == CU-wide DS-pipe
// demand (32 waves x 32 iters x ~38cyc). DS is co-saturated and all waves
// convoy (same loop phase -> burst 128 loads -> all stall at WAITLG).
// Fix: (1) ds_read2_b64 merges the two gathers (4 -> 3 DS ops/iter),
// (2) wave w starts its ring walk at iteration 8*w (4-phase stagger; the
// DOUBLED ring makes the wrap free: ring[k+64]==ring[k], so the carried
// W register is already correct across the wrap — only the issue pointer
// resets, one wave-uniform branch).
__global__ __launch_bounds__(64 * WPB, 8) void match_fused(
        const float* __restrict__ pred0,
        const float* __restrict__ pred1,
        const float* __restrict__ gt,
        float* __restrict__ ws) {
    __shared__ __align__(16) _Float16 lds[WPB][1024];  // ring 1024B | q0 512B | q1 512B
    __shared__ float bsum[WPB];

    const int t = threadIdx.x;
    const int k = t & 63;
    const int w = __builtin_amdgcn_readfirstlane(t >> 6);
    const int b = blockIdx.x * WPB + w;

    _Float16* base = lds[w];
    uint2* ringU = (uint2*)base;              // 128 entries (doubled ring)
    uint2* q0s   = (uint2*)(base + 512);      // byte 1024
    uint2* q1s   = (uint2*)(base + 768);      // byte 1536

    // ---- stage + f32->f16 convert (own wave's region; no barrier needed) ----
    const float4* gv4 = (const float4*)(gt    + (size_t)b * (PNUM * 2));
    const float4* p0v = (const float4*)(pred0 + (size_t)b * (PNUM * 2));
    const float4* p1v = (const float4*)(pred1 + (size_t)b * (PNUM * 2));
    {
        float4 g = gv4[k];
        uint2 gh = {cvt2u(g.x, g.y), cvt2u(g.z, g.w)};
        ringU[k] = gh; ringU[k + 64] = gh;
        float4 p = p0v[k];
        q0s[k] = (uint2){cvt2u(p.x, p.y), cvt2u(p.z, p.w)};
        p = p1v[k];
        q1s[k] = (uint2){cvt2u(p.x, p.y), cvt2u(p.z, p.w)};
    }

    // raw LDS byte addresses for asm DS ops
    const u32 ldsb = (u32)(uintptr_t)base;
    const u32 gA0 = ldsb + (u32)(k * 8);   // ring gather base (lane-sliding)
    const u32 pA0 = ldsb + 1024;           // pred broadcast base (wave-uniform)

    // drain staging ds_writes before asm reads
    asm volatile("s_waitcnt lgkmcnt(0)" ::: "memory");
    __builtin_amdgcn_sched_barrier(0);

    const u32 cOne = 0x3C003C00u;      // packed f16 {1.0, 1.0}
    const u32 cNegHalf = 0xB800B800u;  // packed f16 {-0.5, -0.5}

    // ---- staggered prologue: wave phase h0 = 8*w ----
    const int h0 = w * 8;
    int ii = h0;
    u32 issGA = gA0 + (u32)(16 * h0);
    u32 issPA = pA0 + (u32)(16 * h0);

    u32x2 Wsp;                 // W for first iteration = ring[k + 2*h0]
    DSR64(Wsp, issGA);
    u32x4 b0g, b0q0, b0q1, b1g, b1q0, b1q1, b2g, b2q0, b2q1;
    ISSUE(b0g, b0q0, b0q1);    // iter h0
    ISSUE(b1g, b1q0, b1q1);    // iter h0+1   (no wrap possible in prologue)

    float a00 = 0.f, a01 = 0.f, a10 = 0.f, a11 = 0.f;

    // ---- r=0,1,2 (first trio seeds the W chain from Wsp) ----
    WAITLG(3); COMPUTE(b0g, b0q0, b0q1, Wsp[0], Wsp[1]); ISSUE(b2g, b2q0, b2q1);
    WAITLG(3); COMPUTE(b1g, b1q0, b1q1, b0g[2], b0g[3]); ISSUE(b0g, b0q0, b0q1);
    WAITLG(3); COMPUTE(b2g, b2q0, b2q1, b1g[2], b1g[3]); ISSUE(b1g, b1q0, b1q1);

#pragma unroll 1
    for (int tr = 0; tr < 9; ++tr) {   // r = 3..29
        WAITLG(3); COMPUTE(b0g, b0q0, b0q1, b2g[2], b2g[3]); ISSUE(b2g, b2q0, b2q1);
        WAITLG(3); COMPUTE(b1g, b1q0, b1q1, b0g[2], b0g[3]); ISSUE(b0g, b0q0, b0q1);
        WAITLG(3); COMPUTE(b2g, b2q0, b2q1, b1g[2], b1g[3]); ISSUE(b1g, b1q0, b1q1);
    }
    // ---- epilogue: r=30 (b0), r=31 (b1) ----
    WAITLG(3); COMPUTE(b0g, b0q0, b0q1, b2g[2], b2g[3]);
    WAITLG(0); COMPUTE(b1g, b1q0, b1q1, b0g[2], b0g[3]);

    // per-pred min over lane's 2 shifts, then over the wave
    float r0 = fminf(a00, a01);
    float r1 = fminf(a10, a11);
#pragma unroll
    for (int m = 32; m > 0; m >>= 1) {
        r0 = fminf(r0, __shfl_xor(r0, m, 64));
        r1 = fminf(r1, __shfl_xor(r1, m, 64));
    }

    if (k == 0) bsum[w] = r0 + r1;
    __syncthreads();
    if (t == 0) {
        // plain store, 2048 distinct addresses -> no cross-XCD RMW chain
        ws[blockIdx.x] = bsum[0] + bsum[1] + bsum[2] + bsum[3];
    }
}

// Second dispatch: sum 2048 per-block partials, scale, write out.
__global__ __launch_bounds__(256) void reduce_out(
        const float* __restrict__ ws, float* __restrict__ out) {
    const int t = threadIdx.x;
    const float4* w4 = (const float4*)ws;
    float4 v0 = w4[t];           // 256 * 4 = 1024 partials
    float4 v1 = w4[t + 256];     // + 1024 = 2048
    float s = ((v0.x + v0.y) + (v0.z + v0.w)) + ((v1.x + v1.y) + (v1.z + v1.w));
#pragma unroll
    for (int m = 32; m > 0; m >>= 1) s += __shfl_xor(s, m, 64);
    __shared__ float acc[4];
    const int w = t >> 6;
    if ((t & 63) == 0) acc[w] = s;
    __syncthreads();
    if (t == 0)
        out[0] = (acc[0] + acc[1] + acc[2] + acc[3]) * (1.0f / (2.0f * BATCH * PNUM));
}

extern "C" void kernel_launch(void* const* d_in, const int* in_sizes, int n_in,
                              void* d_out, int out_size, void* d_ws, size_t ws_size,
                              hipStream_t stream) {
    const float* pred0 = (const float*)d_in[0];
    const float* pred1 = (const float*)d_in[1];
    const float* gt    = (const float*)d_in[2];
    float* out = (float*)d_out;
    float* ws  = (float*)d_ws;      // 2048 floats = 8 KB of workspace

    match_fused<<<GRID1, 64 * WPB, 0, stream>>>(pred0, pred1, gt, ws);
    reduce_out<<<1, 256, 0, stream>>>(ws, out);
}

// Round 7
// 109.828 us; speedup vs baseline: 1.0947x; 1.0262x over previous
//
#include <hip/hip_runtime.h>
#include <stdint.h>

#define PNUM 128
#define BATCH 8192
#define WPB 4                      // waves per block, 1 batch per wave
#define GRID1 (BATCH / WPB)        // 2048 blocks of 256 threads

typedef uint32_t u32;
typedef uint32_t u32x2 __attribute__((ext_vector_type(2)));
typedef uint32_t u32x4 __attribute__((ext_vector_type(4)));

// f32x2 -> f16x2 (RTZ) packed into one u32
__device__ __forceinline__ u32 cvt2u(float x, float y) {
    return __builtin_bit_cast(u32, __builtin_amdgcn_cvt_pkrtz(x, y));
}

#define DSR64(dst, addr) \
    asm volatile("ds_read_b64 %0, %1" : "=v"(dst) : "v"(addr))
#define DSR128(dst, addr, OFF) \
    asm volatile("ds_read_b128 %0, %1 offset:" OFF : "=v"(dst) : "v"(addr))
#define DSR2x64(dst, addr) \
    asm volatile("ds_read2_b64 %0, %1 offset0:1 offset1:2" : "=v"(dst) : "v"(addr))
#define WAITLG(N) \
    asm volatile("s_waitcnt lgkmcnt(" #N ")" ::: "memory"); \
    __builtin_amdgcn_sched_barrier(0)

// R12: the bottleneck (finally isolated by elimination + busy-cycle math) is
// IN-ORDER ISSUE ON A 5-INSTR DEPENDENCY CHAIN: dur*VALUBusy/instr ~= 4cyc
// for both R9 and R10 => each wave issues ~1 instr per ALU-latency, and at
// ~4 resident waves/SIMD (Occupancy 48% every round) the SIMD can't fill.
// Fix: interleave FOUR units stage-by-stage (d x4, |d| x4, min x4, fma x4,
// dot2 x4), each quad targeting 4 DIFFERENT accumulators -> consecutive
// instructions are always independent; dependent pairs are 4 apart.
// Per-accumulator accumulation order is unchanged -> bitwise-identical.
#define QUAD(p0,q0,A0, p1,q1,A1, p2,q2,A2, p3,q3,A3) do { \
    u32 d0_, d1_, d2_, d3_, m0_, m1_, m2_, m3_, t0_, t1_, t2_, t3_; \
    asm("v_pk_add_f16 %0, %1, %2 neg_lo:[0,1] neg_hi:[0,1]" : "=v"(d0_) : "v"(p0), "v"(q0)); \
    asm("v_pk_add_f16 %0, %1, %2 neg_lo:[0,1] neg_hi:[0,1]" : "=v"(d1_) : "v"(p1), "v"(q1)); \
    asm("v_pk_add_f16 %0, %1, %2 neg_lo:[0,1] neg_hi:[0,1]" : "=v"(d2_) : "v"(p2), "v"(q2)); \
    asm("v_pk_add_f16 %0, %1, %2 neg_lo:[0,1] neg_hi:[0,1]" : "=v"(d3_) : "v"(p3), "v"(q3)); \
    asm("v_and_b32 %0, 0x7fff7fff, %0" : "+v"(d0_)); \
    asm("v_and_b32 %0, 0x7fff7fff, %0" : "+v"(d1_)); \
    asm("v_and_b32 %0, 0x7fff7fff, %0" : "+v"(d2_)); \
    asm("v_and_b32 %0, 0x7fff7fff, %0" : "+v"(d3_)); \
    asm("v_pk_min_f16 %0, %1, %2" : "=v"(m0_) : "v"(d0_), "v"(cOne)); \
    asm("v_pk_min_f16 %0, %1, %2" : "=v"(m1_) : "v"(d1_), "v"(cOne)); \
    asm("v_pk_min_f16 %0, %1, %2" : "=v"(m2_) : "v"(d2_), "v"(cOne)); \
    asm("v_pk_min_f16 %0, %1, %2" : "=v"(m3_) : "v"(d3_), "v"(cOne)); \
    asm("v_pk_fma_f16 %0, %1, %2, %3" : "=v"(t0_) : "v"(m0_), "v"(cNegHalf), "v"(d0_)); \
    asm("v_pk_fma_f16 %0, %1, %2, %3" : "=v"(t1_) : "v"(m1_), "v"(cNegHalf), "v"(d1_)); \
    asm("v_pk_fma_f16 %0, %1, %2, %3" : "=v"(t2_) : "v"(m2_), "v"(cNegHalf), "v"(d2_)); \
    asm("v_pk_fma_f16 %0, %1, %2, %3" : "=v"(t3_) : "v"(m3_), "v"(cNegHalf), "v"(d3_)); \
    asm("v_dot2_f32_f16 %0, %1, %2, %0" : "+v"(A0) : "v"(m0_), "v"(t0_)); \
    asm("v_dot2_f32_f16 %0, %1, %2, %0" : "+v"(A1) : "v"(m1_), "v"(t1_)); \
    asm("v_dot2_f32_f16 %0, %1, %2, %0" : "+v"(A2) : "v"(m2_), "v"(t2_)); \
    asm("v_dot2_f32_f16 %0, %1, %2, %0" : "+v"(A3) : "v"(m3_), "v"(t3_)); \
} while (0)

// One iteration = 16 units = 4 quads. Quad q holds units {q, q+4, q+8, q+12}
// -> 4 distinct accumulators per quad; same per-acc order as R9.
#define ISSUE(Bg, Bq0, Bq1) \
    DSR2x64(Bg, issGA); \
    DSR128(Bq0, issPA, "0"); \
    DSR128(Bq1, issPA, "512"); \
    issGA += 16; issPA += 16

#define COMPUTE(G, Q0, Q1, W0, W1, DO_ISSUE) \
    QUAD(Q0[0], W0,   a00,  Q0[0], W1,   a01,  Q1[0], W0,   a10,  Q1[0], W1,   a11); \
    DO_ISSUE; \
    QUAD(Q0[1], W1,   a00,  Q0[1], G[0], a01,  Q1[1], W1,   a10,  Q1[1], G[0], a11); \
    QUAD(Q0[2], G[0], a00,  Q0[2], G[1], a01,  Q1[2], G[0], a10,  Q1[2], G[1], a11); \
    QUAD(Q0[3], G[1], a00,  Q0[3], G[2], a01,  Q1[3], G[1], a10,  Q1[3], G[2], a11)

// One WAVE per batch, both preds. Lane k owns shifts {2k,2k+1}.
// Memory structure: R9/R11's verified triple-buffered asm DS pipeline,
// 3 DS ops/iter (ds_read2_b64 merged gather), linear walk, no atomics.
__global__ __launch_bounds__(64 * WPB, 4) void match_fused(
        const float* __restrict__ pred0,
        const float* __restrict__ pred1,
        const float* __restrict__ gt,
        float* __restrict__ ws) {
    __shared__ __align__(16) _Float16 lds[WPB][1024];  // ring 1024B | q0 512B | q1 512B
    __shared__ float bsum[WPB];

    const int t = threadIdx.x;
    const int k = t & 63;
    const int w = __builtin_amdgcn_readfirstlane(t >> 6);
    const int b = blockIdx.x * WPB + w;

    _Float16* base = lds[w];
    uint2* ringU = (uint2*)base;              // 128 entries (doubled ring)
    uint2* q0s   = (uint2*)(base + 512);      // byte 1024
    uint2* q1s   = (uint2*)(base + 768);      // byte 1536

    // ---- stage + f32->f16 convert (own wave's region; no barrier needed) ----
    const float4* gv4 = (const float4*)(gt    + (size_t)b * (PNUM * 2));
    const float4* p0v = (const float4*)(pred0 + (size_t)b * (PNUM * 2));
    const float4* p1v = (const float4*)(pred1 + (size_t)b * (PNUM * 2));
    {
        float4 g = gv4[k];
        uint2 gh = {cvt2u(g.x, g.y), cvt2u(g.z, g.w)};
        ringU[k] = gh; ringU[k + 64] = gh;
        float4 p = p0v[k];
        q0s[k] = (uint2){cvt2u(p.x, p.y), cvt2u(p.z, p.w)};
        p = p1v[k];
        q1s[k] = (uint2){cvt2u(p.x, p.y), cvt2u(p.z, p.w)};
    }

    // raw LDS byte addresses for asm DS ops
    const u32 ldsb = (u32)(uintptr_t)base;
    u32 issGA = ldsb + (u32)(k * 8);   // ring gather base (lane-sliding)
    u32 issPA = ldsb + 1024;           // pred broadcast base (wave-uniform)

    // drain staging ds_writes before asm reads
    asm volatile("s_waitcnt lgkmcnt(0)" ::: "memory");
    __builtin_amdgcn_sched_barrier(0);

    const u32 cOne = 0x3C003C00u;      // packed f16 {1.0, 1.0}
    const u32 cNegHalf = 0xB800B800u;  // packed f16 {-0.5, -0.5}

    // ---- prologue: W(iter0)=ring[k]; issue iter0 (buf0), iter1 (buf1) ----
    u32x2 Wsp;
    DSR64(Wsp, issGA);                 // seed W; issGA unchanged (offset 0)
    u32x4 b0g, b0q0, b0q1, b1g, b1q0, b1q1, b2g, b2q0, b2q1;
    ISSUE(b0g, b0q0, b0q1);            // iter 0
    ISSUE(b1g, b1q0, b1q1);            // iter 1
    // outstanding: Wsp(1) + iter0(3) + iter1(3) = 7

    float a00 = 0.f, a01 = 0.f, a10 = 0.f, a11 = 0.f;

    // ---- peeled first trio (W chain seeded from Wsp) ----
    WAITLG(3); COMPUTE(b0g, b0q0, b0q1, Wsp[0], Wsp[1], ISSUE(b2g, b2q0, b2q1));
    WAITLG(3); COMPUTE(b1g, b1q0, b1q1, b0g[2], b0g[3], ISSUE(b0g, b0q0, b0q1));
    WAITLG(3); COMPUTE(b2g, b2q0, b2q1, b1g[2], b1g[3], ISSUE(b1g, b1q0, b1q1));

#pragma unroll 1
    for (int tr = 0; tr < 9; ++tr) {   // iters 3..29
        WAITLG(3); COMPUTE(b0g, b0q0, b0q1, b2g[2], b2g[3], ISSUE(b2g, b2q0, b2q1));
        WAITLG(3); COMPUTE(b1g, b1q0, b1q1, b0g[2], b0g[3], ISSUE(b0g, b0q0, b0q1));
        WAITLG(3); COMPUTE(b2g, b2q0, b2q1, b1g[2], b1g[3], ISSUE(b1g, b1q0, b1q1));
    }
    // ---- epilogue: iters 30 (b0), 31 (b1) ----
    WAITLG(3); COMPUTE(b0g, b0q0, b0q1, b2g[2], b2g[3], );
    WAITLG(0); COMPUTE(b1g, b1q0, b1q1, b0g[2], b0g[3], );

    // per-pred min over lane's 2 shifts, then over the wave
    float r0 = fminf(a00, a01);
    float r1 = fminf(a10, a11);
#pragma unroll
    for (int m = 32; m > 0; m >>= 1) {
        r0 = fminf(r0, __shfl_xor(r0, m, 64));
        r1 = fminf(r1, __shfl_xor(r1, m, 64));
    }

    if (k == 0) bsum[w] = r0 + r1;
    __syncthreads();
    if (t == 0) {
        // plain store, 2048 distinct addresses -> no cross-XCD RMW chain
        ws[blockIdx.x] = bsum[0] + bsum[1] + bsum[2] + bsum[3];
    }
}

// Second dispatch: sum 2048 per-block partials, scale, write out.
__global__ __launch_bounds__(256) void reduce_out(
        const float* __restrict__ ws, float* __restrict__ out) {
    const int t = threadIdx.x;
    const float4* w4 = (const float4*)ws;
    float4 v0 = w4[t];           // 256 * 4 = 1024 partials
    float4 v1 = w4[t + 256];     // + 1024 = 2048
    float s = ((v0.x + v0.y) + (v0.z + v0.w)) + ((v1.x + v1.y) + (v1.z + v1.w));
#pragma unroll
    for (int m = 32; m > 0; m >>= 1) s += __shfl_xor(s, m, 64);
    __shared__ float acc[4];
    const int w = t >> 6;
    if ((t & 63) == 0) acc[w] = s;
    __syncthreads();
    if (t == 0)
        out[0] = (acc[0] + acc[1] + acc[2] + acc[3]) * (1.0f / (2.0f * BATCH * PNUM));
}

extern "C" void kernel_launch(void* const* d_in, const int* in_sizes, int n_in,
                              void* d_out, int out_size, void* d_ws, size_t ws_size,
                              hipStream_t stream) {
    const float* pred0 = (const float*)d_in[0];
    const float* pred1 = (const float*)d_in[1];
    const float* gt    = (const float*)d_in[2];
    float* out = (float*)d_out;
    float* ws  = (float*)d_ws;      // 2048 floats = 8 KB of workspace

    match_fused<<<GRID1, 64 * WPB, 0, stream>>>(pred0, pred1, gt, ws);
    reduce_out<<<1, 256, 0, stream>>>(ws, out);
}